// Round 6
// baseline (186.769 us; speedup 1.0000x reference)
//
#include <hip/hip_runtime.h>
#include <cstdint>
#include <cstddef>

using u32 = unsigned int;
using u64 = unsigned long long;

typedef int v4i  __attribute__((ext_vector_type(4)));
typedef int v16i __attribute__((ext_vector_type(16)));

#define EPSV 1e-5f

// ---------------------------------------------------------------------------
// Kernel 1: weight prep. One block per (co, conv). 256 threads = 256 in-chans.
// Wsgn[conv][co][p][c] i8 = sign(w - mean); SC4 = (alpha, scale, shift, 0)
// with IEEE ops in the reference's exact order.
// ---------------------------------------------------------------------------
__global__ void prep_weights(const float* __restrict__ w1, const float* __restrict__ w2,
                             const float* __restrict__ a1, const float* __restrict__ g1,
                             const float* __restrict__ b1, const float* __restrict__ m1,
                             const float* __restrict__ v1,
                             const float* __restrict__ a2, const float* __restrict__ g2,
                             const float* __restrict__ b2, const float* __restrict__ m2,
                             const float* __restrict__ v2,
                             unsigned char* __restrict__ Wsgn, float4* __restrict__ SC4)
{
    const int co   = blockIdx.x;
    const int conv = blockIdx.y;
    const int c    = threadIdx.x;
    const float* w = conv ? w2 : w1;

    float wv[9];
    const float* wp = w + ((size_t)co * 256 + c) * 9;
    float s = 0.f;
#pragma unroll
    for (int p = 0; p < 9; ++p) { wv[p] = wp[p]; s += wv[p]; }

    __shared__ float red[256];
    red[c] = s;
    __syncthreads();
    for (int off = 128; off > 0; off >>= 1) {
        if (c < off) red[c] += red[c + off];
        __syncthreads();
    }
    const float mean = __fdiv_rn(red[0], 2304.0f);

    unsigned char* wrow = Wsgn + ((size_t)(conv * 256 + co) * 9) * 256;
#pragma unroll
    for (int p = 0; p < 9; ++p)
        wrow[p * 256 + c] = (wv[p] > mean) ? 0x01u : 0xFFu;

    if (c == 0) {
        const float alpha = conv ? a2[co] : a1[co];
        const float gamma = conv ? g2[co] : g1[co];
        const float beta  = conv ? b2[co] : b1[co];
        const float mu    = conv ? m2[co] : m1[co];
        const float var   = conv ? v2[co] : v1[co];
        const float sq    = __fsqrt_rn(__fadd_rn(var, EPSV));
        const float scale = __fdiv_rn(gamma, sq);
        const float shift = __fsub_rn(beta, __fdiv_rn(__fmul_rn(mu, gamma), sq));
        SC4[conv * 256 + co] = make_float4(alpha, scale, shift, 0.f);
    }
}

// ---------------------------------------------------------------------------
// Kernel 2: B fragments in exact mfma_i32_32x32x32_i8 operand order.
// Frag f = conv*576 + g*72 + p*8 + cb. Lane l: B[k=(l>>5)*16+j][n=l&31].
// ---------------------------------------------------------------------------
__global__ void build_bfrag(const unsigned char* __restrict__ Wsgn, uint4* __restrict__ Bf)
{
    const int f    = blockIdx.x;           // 0..1151
    const int lane = threadIdx.x;          // 0..63
    const int conv = f / 576;
    const int rem  = f % 576;
    const int g    = rem / 72;
    const int p    = (rem % 72) / 8;
    const int cb   = rem % 8;
    const int co   = g * 32 + (lane & 31);
    const unsigned char* src = Wsgn + ((size_t)(conv * 256 + co) * 9 + p) * 256
                                    + cb * 32 + (lane >> 5) * 16;
    Bf[(size_t)f * 64 + lane] = *(const uint4*)src;
}

// ---------------------------------------------------------------------------
// Kernel 3: binarize x -> packed bits. A[n][pixel][j], j = chan/32.
// ---------------------------------------------------------------------------
__global__ void binarize_x(const float* __restrict__ x, u32* __restrict__ A1)
{
    const int n = blockIdx.x >> 3;
    const int j = blockIdx.x & 7;
    const int p = threadIdx.x;
    const float* xp = x + (((size_t)n * 256 + j * 32) * 1024) + p;
    u32 bits = 0;
#pragma unroll
    for (int k = 0; k < 32; ++k) {
        float v = xp[(size_t)k * 1024];
        bits |= (v > 0.f ? 1u : 0u) << k;
    }
    A1[((size_t)n * 1024 + p) * 8 + j] = bits;
}

__device__ __forceinline__ u32 expand4(u32 x)
{
    u32 r;
    r  = ((x & 1u) ? 0x00000001u : 0x000000FFu);
    r |= ((x & 2u) ? 0x00000100u : 0x0000FF00u);
    r |= ((x & 4u) ? 0x00010000u : 0x00FF0000u);
    r |= ((x & 8u) ? 0x01000000u : 0xFF000000u);
    return r;
}

// ---------------------------------------------------------------------------
// Kernel 4/5: binary conv as i8 MFMA GEMM, big-tile version.
// Block: 256 thr = 4 waves, covers 4 rows x 32 cols x ALL 256 cos.
// Wave w: co-groups g0=2w, g1=2w+1 (64 cos) x 4 rows = 8 v16i accumulators.
// Grid: 64 n x 8 yquads = 512 blocks (2 per CU).
//
// LDS act tile: [c16 0..15][row 0..5][xs 0..33] cells of 16B = 52,224 B.
// granule%8 = xs%8 -> ds_read_b128 conflict-free WITHOUT any XOR; every
// A-fragment address = lane base + compile-time immediate (max 48,448).
// Per k-step (9 pos x 8 ch-blocks): 4 ds_read_b128 + 2 B global loads +
// 8 mfma  ->  ds/mfma = 0.5, B-bytes/mfma = 256 (B L2 traffic 295 MB/conv).
// Tile is K-resident: NO barriers in the main loop.
//
// A: m(=x) = l&31, k = (l>>5)*16+j ; B: n(=co) = l&31 ; C/D: n = l&31,
// m = (reg&3)+8*(reg>>2)+4*(l>>5)   [R5-verified on HW].
//
// CONV==1: t = (dot*alpha)*scale+shift; packed sign bits via __ballot.
// CONV==2: per-row LDS transpose ep[x][co] (pad 257) -> coalesced
//          clamp(t + X) float4 stores.
// ---------------------------------------------------------------------------
template<int CONV>
__global__ __launch_bounds__(256, 1)
void conv_mfma(const u32* __restrict__ A_in, const v4i* __restrict__ Bf,
               const float4* __restrict__ SC4, const float* __restrict__ X,
               u32* __restrict__ A_out, float* __restrict__ OUT)
{
    const int n    = blockIdx.x >> 3;
    const int yq   = blockIdx.x & 7;
    const int y0   = yq * 4;
    const int tid  = threadIdx.x;
    const int wave = tid >> 6;
    const int lane = tid & 63;

    __shared__ alignas(16) unsigned char lds[52224];

    // ---- stage: packed bits -> i8 tile [c16][r][xs], halo rows/cols -> 0 ----
    for (int s = tid; s < 3264; s += 256) {
        const int xs   = s % 34;
        const int rest = s / 34;
        const int r    = rest % 6;          // image row y0-1+r
        const int c16  = rest / 6;          // 16-channel group
        const int iy   = y0 - 1 + r;
        const int ix   = xs - 1;
        u32 d0 = 0, d1 = 0, d2 = 0, d3 = 0;
        if ((unsigned)iy < 32u && (unsigned)ix < 32u) {
            const u32 wrd = A_in[((size_t)n * 1024 + iy * 32 + ix) * 8 + (c16 >> 1)];
            const u32 h = (wrd >> ((c16 & 1) * 16)) & 0xFFFFu;
            d0 = expand4(h);
            d1 = expand4(h >> 4);
            d2 = expand4(h >> 8);
            d3 = expand4(h >> 12);
        }
        *(uint4*)(lds + ((c16 * 6 + r) * 34 + xs) * 16) = make_uint4(d0, d1, d2, d3);
    }
    __syncthreads();

    // ---- K-loop: 72 steps, fully unrolled, barrier-free ----
    const v16i Z = {0,0,0,0,0,0,0,0,0,0,0,0,0,0,0,0};
    v16i acc00 = Z, acc01 = Z, acc10 = Z, acc11 = Z;
    v16i acc20 = Z, acc21 = Z, acc30 = Z, acc31 = Z;

    const int g0 = wave * 2, g1 = g0 + 1;
    const v4i* B0 = Bf + ((size_t)(((CONV == 2) ? 576 : 0) + g0 * 72)) * 64 + lane;
    const v4i* B1 = Bf + ((size_t)(((CONV == 2) ? 576 : 0) + g1 * 72)) * 64 + lane;
    const u32 labase = (u32)((lane >> 5) * 3264 + (lane & 31) * 16);

#pragma unroll
    for (int p = 0; p < 9; ++p) {
        const int dy = p / 3, dx = p % 3;
#pragma unroll
        for (int cb = 0; cb < 8; ++cb) {
            const v4i b0 = B0[(p * 8 + cb) * 64];
            const v4i b1 = B1[(p * 8 + cb) * 64];
            const u32 ob = labase + (u32)(cb * 6528 + dy * 544 + dx * 16);
            const v4i a0 = *(const v4i*)(lds + ob);
            const v4i a1 = *(const v4i*)(lds + ob + 544);
            const v4i a2 = *(const v4i*)(lds + ob + 1088);
            const v4i a3 = *(const v4i*)(lds + ob + 1632);
            acc00 = __builtin_amdgcn_mfma_i32_32x32x32_i8(a0, b0, acc00, 0, 0, 0);
            acc01 = __builtin_amdgcn_mfma_i32_32x32x32_i8(a0, b1, acc01, 0, 0, 0);
            acc10 = __builtin_amdgcn_mfma_i32_32x32x32_i8(a1, b0, acc10, 0, 0, 0);
            acc11 = __builtin_amdgcn_mfma_i32_32x32x32_i8(a1, b1, acc11, 0, 0, 0);
            acc20 = __builtin_amdgcn_mfma_i32_32x32x32_i8(a2, b0, acc20, 0, 0, 0);
            acc21 = __builtin_amdgcn_mfma_i32_32x32x32_i8(a2, b1, acc21, 0, 0, 0);
            acc30 = __builtin_amdgcn_mfma_i32_32x32x32_i8(a3, b0, acc30, 0, 0, 0);
            acc31 = __builtin_amdgcn_mfma_i32_32x32x32_i8(a3, b1, acc31, 0, 0, 0);
        }
    }

    const int col = lane & 31;
    const float4 sc0 = SC4[((CONV == 2) ? 256 : 0) + g0 * 32 + col];
    const float4 sc1 = SC4[((CONV == 2) ? 256 : 0) + g1 * 32 + col];

    if (CONV == 1) {
#define EP1(ACC, RY, G, SC)                                                     \
        { _Pragma("unroll")                                                     \
          for (int reg = 0; reg < 16; ++reg) {                                  \
              const float t = __fadd_rn(__fmul_rn(__fmul_rn((float)ACC[reg],    \
                                        SC.x), SC.y), SC.z);                    \
              const u64 m = __ballot(t > 0.f);                                  \
              if (lane == 0) {                                                  \
                  const int x = (reg & 3) + 8 * (reg >> 2);                     \
                  const size_t pb = (size_t)n * 1024 + (y0 + (RY)) * 32 + x;    \
                  A_out[pb * 8 + (G)]       = (u32)m;                           \
                  A_out[(pb + 4) * 8 + (G)] = (u32)(m >> 32);                   \
              } } }
        EP1(acc00, 0, g0, sc0)  EP1(acc01, 0, g1, sc1)
        EP1(acc10, 1, g0, sc0)  EP1(acc11, 1, g1, sc1)
        EP1(acc20, 2, g0, sc0)  EP1(acc21, 2, g1, sc1)
        EP1(acc30, 3, g0, sc0)  EP1(acc31, 3, g1, sc1)
#undef EP1
    } else {
        __syncthreads();                    // act tile reads done
        float* ep = (float*)lds;            // ep[x][co] pad 257 = 32.9 KB
#define EP2PASS(A0, A1, RY)                                                     \
        { _Pragma("unroll")                                                     \
          for (int reg = 0; reg < 16; ++reg) {                                  \
              const int x = (reg & 3) + 8 * (reg >> 2) + 4 * (lane >> 5);       \
              const float t0 = __fadd_rn(__fmul_rn(__fmul_rn((float)A0[reg],    \
                                         sc0.x), sc0.y), sc0.z);                \
              const float t1 = __fadd_rn(__fmul_rn(__fmul_rn((float)A1[reg],    \
                                         sc1.x), sc1.y), sc1.z);                \
              ep[x * 257 + g0 * 32 + col] = t0;                                 \
              ep[x * 257 + g1 * 32 + col] = t1;                                 \
          }                                                                     \
          __syncthreads();                                                      \
          {                                                                     \
              const int co = tid;                                               \
              const size_t gb = ((size_t)(n * 256 + co)) * 1024                 \
                              + (y0 + (RY)) * 32;                               \
              _Pragma("unroll")                                                 \
              for (int x4 = 0; x4 < 32; x4 += 4) {                              \
                  float4 r;                                                     \
                  r.x = ep[(x4 + 0) * 257 + co];                                \
                  r.y = ep[(x4 + 1) * 257 + co];                                \
                  r.z = ep[(x4 + 2) * 257 + co];                                \
                  r.w = ep[(x4 + 3) * 257 + co];                                \
                  const float4 xv = *(const float4*)(X + gb + x4);              \
                  r.x = fminf(1.f, fmaxf(-1.f, __fadd_rn(r.x, xv.x)));          \
                  r.y = fminf(1.f, fmaxf(-1.f, __fadd_rn(r.y, xv.y)));          \
                  r.z = fminf(1.f, fmaxf(-1.f, __fadd_rn(r.z, xv.z)));          \
                  r.w = fminf(1.f, fmaxf(-1.f, __fadd_rn(r.w, xv.w)));          \
                  *(float4*)(OUT + gb + x4) = r;                                \
              }                                                                 \
          }                                                                     \
          __syncthreads(); }
        EP2PASS(acc00, acc01, 0)
        EP2PASS(acc10, acc11, 1)
        EP2PASS(acc20, acc21, 2)
        EP2PASS(acc30, acc31, 3)
#undef EP2PASS
    }
}

// ---------------------------------------------------------------------------
extern "C" void kernel_launch(void* const* d_in, const int* in_sizes, int n_in,
                              void* d_out, int out_size, void* d_ws, size_t ws_size,
                              hipStream_t stream)
{
    const float* x   = (const float*)d_in[0];
    const float* w1  = (const float*)d_in[1];
    const float* al1 = (const float*)d_in[2];
    const float* g1  = (const float*)d_in[3];
    const float* b1  = (const float*)d_in[4];
    const float* m1  = (const float*)d_in[5];
    const float* v1  = (const float*)d_in[6];
    const float* w2  = (const float*)d_in[7];
    const float* al2 = (const float*)d_in[8];
    const float* g2  = (const float*)d_in[9];
    const float* b2  = (const float*)d_in[10];
    const float* m2  = (const float*)d_in[11];
    const float* v2  = (const float*)d_in[12];
    float* out = (float*)d_out;

    char* ws = (char*)d_ws;
    float4*        SC4  = (float4*)(ws);                        //   8 KB
    unsigned char* Wsgn = (unsigned char*)(ws + (64u << 10));   // 1.18 MB
    uint4*         Bf   = (uint4*)(ws + (2u << 20));            // 1.18 MB
    u32*           A1   = (u32*)(ws + (4u << 20));              // 2 MB
    u32*           A2   = (u32*)(ws + (6u << 20));              // 2 MB
    (void)ws_size; (void)in_sizes; (void)n_in; (void)out_size;

    prep_weights<<<dim3(256, 2), 256, 0, stream>>>(w1, w2, al1, g1, b1, m1, v1,
                                                   al2, g2, b2, m2, v2, Wsgn, SC4);
    build_bfrag<<<dim3(1152), 64, 0, stream>>>(Wsgn, Bf);
    binarize_x<<<dim3(512), 1024, 0, stream>>>(x, A1);
    conv_mfma<1><<<dim3(512), 256, 0, stream>>>(A1, (const v4i*)Bf, SC4,
                                                nullptr, A2, nullptr);
    conv_mfma<2><<<dim3(512), 256, 0, stream>>>(A2, (const v4i*)Bf, SC4,
                                                x, nullptr, out);
}